// Round 11
// baseline (130.798 us; speedup 1.0000x reference)
//
#include <hip/hip_runtime.h>
#include <math.h>

#define NB 2
#define NR 16384
#define NRAY (NB*NR)   // 32768 rays
#define NS 48
#define NC 32
#define ND 64
#define NBLK (NRAY/8)  // 4096 march blocks (4 waves x 2 rays each)

// d_ws layout (floats): [0 .. NBLK) = per-block var partials (vb)
//                       [NBLK .. 2*NBLK) = per-block depth min (bmn)
//                       [2*NBLK .. 3*NBLK) = per-block depth max (bmx)

__global__ __launch_bounds__(256) void march_kernel(
    const float* __restrict__ colors, const float* __restrict__ densities,
    const float* __restrict__ depths, const float* __restrict__ dinos,
    float* __restrict__ out, float* __restrict__ vb,
    float* __restrict__ bmn, float* __restrict__ bmx)
{
    const int wid  = threadIdx.x >> 6;
    const int lane = threadIdx.x & 63;
    const int ray0 = blockIdx.x * 8 + wid * 2;    // this wave: rays ray0, ray0+1

    __shared__ float v_sh[4][2][NS];
    __shared__ float var_sh[4];
    __shared__ float mn_sh[4], mx_sh[4];

    float d_i[2], n_i[2];
#pragma unroll
    for (int r = 0; r < 2; ++r) {
        const float* dep = depths    + (size_t)(ray0 + r) * NS;
        const float* den = densities + (size_t)(ray0 + r) * NS;
        d_i[r] = (lane < NS) ? dep[lane] : 0.f;
        n_i[r] = (lane < NS) ? den[lane] : 0.f;
    }

    const bool act = (lane < NS - 1);             // 47 intervals
    float w[2], W[2], M[2], vn[2], bg[2];
#pragma unroll
    for (int r = 0; r < 2; ++r) {
        float d_n = __shfl_down(d_i[r], 1);
        float n_n = __shfl_down(n_i[r], 1);
        float delta = d_n - d_i[r];
        float dm    = 0.5f * (d_i[r] + d_n);          // depths_mid
        float x     = 0.5f * (n_i[r] + n_n) - 1.0f;   // densities_mid - 1
        float sp    = fmaxf(x, 0.f) + log1pf(expf(-fabsf(x)));   // stable softplus
        float alpha = act ? (1.f - expf(-sp * delta)) : 0.f;
        float f     = act ? (1.f - alpha + 1e-10f) : 1.f;

        // inclusive prefix product (Kogge-Stone) over 64 lanes
        float incl = f;
#pragma unroll
        for (int off = 1; off < 64; off <<= 1) {
            float o = __shfl_up(incl, off);
            if (lane >= off) incl *= o;
        }
        float T = __shfl_up(incl, 1);
        if (lane == 0) T = 1.f;
        w[r]  = alpha * T;                            // lanes >= 47 have w == 0
        bg[r] = __shfl(incl, 45);                     // T_46

        // butterfly reductions: W = sum w, M = sum w*dm
        float Wr = w[r], Mr = w[r] * dm;
#pragma unroll
        for (int off = 32; off > 0; off >>= 1) {
            Wr += __shfl_xor(Wr, off);
            Mr += __shfl_xor(Mr, off);
        }
        W[r] = Wr; M[r] = Mr;
        float dv = dm - Mr;
        float vr = w[r] * dv * dv;
#pragma unroll
        for (int off = 32; off > 0; off >>= 1) vr += __shfl_xor(vr, off);
        vn[r] = vr;

        float wprev = __shfl_up(w[r], 1);
        if (lane == 0) wprev = 0.f;
        float v = 0.5f * (wprev + w[r]);              // v_j = 0.5*(w_{j-1}+w_j)
        if (lane < NS) v_sh[wid][r][lane] = v;        // same-wave LDS RAW: no barrier
    }

    // per-wave depth min/max (sorted along S): endpoints of both rays
    if (lane == 0)      mn_sh[wid] = fminf(d_i[0], d_i[1]);
    if (lane == NS - 1) mx_sh[wid] = fmaxf(d_i[0], d_i[1]);

    // output chunk bases (return order, flat)
    float* out_rgb = out;
    float* out_dep = out + (size_t)NRAY * NC;
    float* out_w   = out + (size_t)NRAY * (NC + 1);
    float* out_bg  = out + (size_t)NRAY * (NC + 1 + (NS - 1));
    float* out_din = out + (size_t)NRAY * (NC + 2 + (NS - 1));
    float* out_wt  = out + (size_t)NRAY * (NC + 2 + (NS - 1) + ND);

#pragma unroll
    for (int r = 0; r < 2; ++r) {
        const int ray = ray0 + r;
        if (act) out_w[(size_t)ray * (NS - 1) + lane] = w[r];
        if (lane == 0) {
            float cd = M[r] / W[r];
            if (cd != cd) cd = INFINITY;              // nan_to_num(nan=inf); clipped by post
            out_dep[ray] = cd;
            out_bg[ray]  = bg[r];
            out_wt[ray]  = W[r];
        }
    }
    if (lane == 0)
        var_sh[wid] = vn[0] / (W[0] + 1e-6f) + vn[1] / (W[1] + 1e-6f);

    // composite_rgb: lane-owns-channel, NO reduce tail.
    // lanes 0-31 = ray0 channels, lanes 32-63 = ray1 channels.
    // Each iteration j: two 128B dense segments (256B/wave-read); store = one 256B dense store.
    {
        const int rsel = lane >> 5;
        const int c    = lane & 31;
        const float* cp = colors + (size_t)(ray0 + rsel) * (NS * NC) + c;
        float acc = 0.f;
#pragma unroll
        for (int j = 0; j < NS; ++j)
            acc += v_sh[wid][rsel][j] * cp[(size_t)j * NC];   // uniform-index LDS broadcast
        out_rgb[(size_t)ray0 * NC + lane] = 2.f * acc - 1.f;  // rows ray0,ray0+1 contiguous
    }

    // composite_dino: lane = channel (64), both rays interleaved; 96 coalesced 256B reads, no shuffles.
    {
        const float* dp0 = dinos + (size_t)ray0 * (NS * ND) + lane;
        const float* dp1 = dinos + (size_t)(ray0 + 1) * (NS * ND) + lane;
        float a0 = 0.f, a1 = 0.f;
#pragma unroll
        for (int j = 0; j < NS; ++j) {
            a0 += v_sh[wid][0][j] * dp0[(size_t)j * ND];
            a1 += v_sh[wid][1][j] * dp1[(size_t)j * ND];
        }
        out_din[(size_t)ray0 * ND + lane]       = 2.f * a0 + (1.f - 2.f * W[0]);
        out_din[(size_t)(ray0 + 1) * ND + lane] = 2.f * a1 + (1.f - 2.f * W[1]);
    }

    __syncthreads();
    if (threadIdx.x == 0) {
        // plain per-block stores; no atomics anywhere
        vb[blockIdx.x]  = var_sh[0] + var_sh[1] + var_sh[2] + var_sh[3];
        bmn[blockIdx.x] = fminf(fminf(mn_sh[0], mn_sh[1]), fminf(mn_sh[2], mn_sh[3]));
        bmx[blockIdx.x] = fmaxf(fmaxf(mx_sh[0], mx_sh[1]), fmaxf(mx_sh[2], mx_sh[3]));
    }
}

// 128 blocks x 256 threads: every block reduces bmn/bmx (4096 each) -> global min/max,
// clips its 256-ray slice of out_dep; block 0 also sums vb -> var mean.
__global__ __launch_bounds__(256) void post_kernel(
    const float* __restrict__ vb, const float* __restrict__ bmn,
    const float* __restrict__ bmx, float* __restrict__ out)
{
    const int tid  = threadIdx.x;
    const int lane = tid & 63;
    __shared__ float smn[4], smx[4], ssum[4];

    float mn = 3.402823466e+38f, mx = -3.402823466e+38f;
    const float4* a4 = (const float4*)bmn;   // 1024 float4
    const float4* b4 = (const float4*)bmx;
    for (int i = tid; i < NBLK / 4; i += 256) {
        float4 a = a4[i], b = b4[i];
        mn = fminf(mn, fminf(fminf(a.x, a.y), fminf(a.z, a.w)));
        mx = fmaxf(mx, fmaxf(fmaxf(b.x, b.y), fmaxf(b.z, b.w)));
    }
#pragma unroll
    for (int off = 32; off > 0; off >>= 1) {
        mn = fminf(mn, __shfl_xor(mn, off));
        mx = fmaxf(mx, __shfl_xor(mx, off));
    }
    if (lane == 0) { smn[tid >> 6] = mn; smx[tid >> 6] = mx; }
    __syncthreads();
    float gmin = fminf(fminf(smn[0], smn[1]), fminf(smn[2], smn[3]));
    float gmax = fmaxf(fmaxf(smx[0], smx[1]), fmaxf(smx[2], smx[3]));

    // clip this block's slice of composite_depth (inf -> gmax)
    float* out_dep = out + (size_t)NRAY * NC;
    int i = blockIdx.x * 256 + tid;
    float cd = out_dep[i];
    out_dep[i] = fminf(fmaxf(cd, gmin), gmax);

    if (blockIdx.x == 0) {
        float s = 0.f;
        const float4* v4 = (const float4*)vb;    // 1024 float4
        for (int i2 = tid; i2 < NBLK / 4; i2 += 256) {
            float4 v = v4[i2];
            s += (v.x + v.y) + (v.z + v.w);
        }
#pragma unroll
        for (int off = 32; off > 0; off >>= 1) s += __shfl_xor(s, off);
        if (lane == 0) ssum[tid >> 6] = s;
        __syncthreads();
        if (tid == 0)
            out[(size_t)NRAY * 146] = (ssum[0] + ssum[1] + ssum[2] + ssum[3]) * (1.0f / (float)NRAY);
    }
}

extern "C" void kernel_launch(void* const* d_in, const int* in_sizes, int n_in,
                              void* d_out, int out_size, void* d_ws, size_t ws_size,
                              hipStream_t stream) {
    const float* colors    = (const float*)d_in[0];
    const float* densities = (const float*)d_in[1];
    const float* depths    = (const float*)d_in[2];
    const float* dinos     = (const float*)d_in[3];
    float* out = (float*)d_out;
    float* vb  = (float*)d_ws;
    float* bmn = vb + NBLK;
    float* bmx = vb + 2 * NBLK;

    hipLaunchKernelGGL(march_kernel, dim3(NBLK), dim3(256), 0, stream,
                       colors, densities, depths, dinos, out, vb, bmn, bmx);
    hipLaunchKernelGGL(post_kernel, dim3(NRAY / 256), dim3(256), 0, stream,
                       (const float*)vb, (const float*)bmn, (const float*)bmx, out);
}